// Round 7
// baseline (96.544 us; speedup 1.0000x reference)
//
#include <hip/hip_runtime.h>

#define BB 4
#define CC 3
#define HH 512
#define WW 512
#define NS 81              // 9 x 9 shifts
#define IMG (HH * WW)
#define CHW (CC * IMG)
#define STRIP 8            // rows per strip
#define NSTRIPS (HH / STRIP)             // 64
#define NBLK (BB * NSTRIPS)              // 256 blocks = exactly 1 per CU
#define NROWS (CC * STRIP)               // 24 row-iterations per wave

// R18: post-R17 model: k_sims ~20-25us (per-row serial HBM stall; VGPR=32
// proves compiler never prefetched), k_reduce ~7-10us (64 divergent 1.5KB
// streams, 4 blocks), k_apply ~9, gaps ~10, fill 43.5 (unconditional).
//  - k_sims: channel-loop inside block (256 blocks, 1/CU -- R17 proved
//    occupancy-neutral), in-register c-accumulation (3x fewer partials),
//    and explicit next-row register double-buffering (rotation) so the
//    cold-HBM load latency overlaps the previous row's 144 FMAs.
//  - k_reduce: transposed g_part[strip][b*81+sim] + ONE 384-thread block:
//    each iteration reads 2.6KB contiguous (coalesced), 64 independent
//    iterations pipeline -> ~2us.
//  - k_apply: unchanged (proven exact since R11).
__device__ double g_part[NSTRIPS][BB * NS];   // [strip][b*81+sim], 166 KB
__device__ int    g_best[BB];

// constant-index component select (folds after full unroll)
#define C4(v, i) ((i) == 0 ? (v).x : (i) == 1 ? (v).y : (i) == 2 ? (v).z : (v).w)

// sim(b,sx,sy) = sum over c,i,j (both (i,j) and (i+sx,j+sy) in bounds) of
//               x[b,c,i,j] * x_ref[b,c,i+sx,j+sy]
__global__ __launch_bounds__(576, 8) void k_sims(const float* __restrict__ xref,
                                                 const float* __restrict__ x) {
    int bid   = blockIdx.x;          // 0..255
    int strip = bid & (NSTRIPS - 1);
    int b     = bid >> 6;
    int tid  = threadIdx.x;
    int lane = tid & 63;
    int sxi  = tid >> 6;             // wave index == sx index (9 waves)
    int j0   = lane << 3;            // 8 floats per lane
    int sx   = sxi - 4;
    int ip0  = strip * STRIP;

    const float* xbase = x    + (size_t)b * CHW;
    const float* rbase = xref + (size_t)b * CHW;

    float acc[9];
#pragma unroll
    for (int s = 0; s < 9; ++s) acc[s] = 0.f;

    // software-pipelined over t = c*8 + rr (24 iterations):
    // registers {xa,xb,ra,rb} hold row t; {nxa..nrb} prefetch row t+1.
    float4 xa, xb, ra, rb, nxa, nxb, nra, nrb;
    bool okc;
    {   // preload t = 0 (c=0, rr=0)
        int ii = ip0 + sx;
        okc = (unsigned)ii < HH;
        const float* xr = xbase + ip0 * WW + j0;
        const float* rr_ = rbase + (okc ? ii : ip0) * WW + j0;  // clamp: value unused if !okc
        xa = *(const float4*)xr;   xb = *(const float4*)(xr + 4);
        ra = *(const float4*)rr_;  rb = *(const float4*)(rr_ + 4);
    }

#pragma unroll 2
    for (int t = 0; t < NROWS; ++t) {
        bool okn = false;
        if (t < NROWS - 1) {         // issue next-row loads BEFORE computing t
            int tn = t + 1;
            int c  = tn >> 3;
            int ip = ip0 + (tn & 7);
            int ii = ip + sx;
            okn = (unsigned)ii < HH;
            const float* xr  = xbase + (size_t)c * IMG + ip * WW + j0;
            const float* rr_ = rbase + (size_t)c * IMG + (okn ? ii : ip) * WW + j0;
            nxa = *(const float4*)xr;   nxb = *(const float4*)(xr + 4);
            nra = *(const float4*)rr_;  nrb = *(const float4*)(rr_ + 4);
        }

        if (okc) {                   // wave-uniform
            // halo: prev4 = ref cols j0-4..j0-1 (lane-1's rb), next4 = j0+8..j0+11
            float p0 = __shfl_up(rb.x, 1, 64);
            float p1 = __shfl_up(rb.y, 1, 64);
            float p2 = __shfl_up(rb.z, 1, 64);
            float p3 = __shfl_up(rb.w, 1, 64);
            if (lane == 0) { p0 = p1 = p2 = p3 = 0.f; }   // cols < 0 -> mask
            float n0 = __shfl_down(ra.x, 1, 64);
            float n1 = __shfl_down(ra.y, 1, 64);
            float n2 = __shfl_down(ra.z, 1, 64);
            float n3 = __shfl_down(ra.w, 1, 64);
            if (lane == 63) { n0 = n1 = n2 = n3 = 0.f; }  // cols >= 512 -> mask

#define P4(i) ((i) == 0 ? p0 : (i) == 1 ? p1 : (i) == 2 ? p2 : p3)
#define N4(i) ((i) == 0 ? n0 : (i) == 1 ? n1 : (i) == 2 ? n2 : n3)
#pragma unroll
            for (int syi = 0; syi < 9; ++syi) {
#pragma unroll
                for (int k = 0; k < 8; ++k) {
                    int i = k + syi;         // window index 0..15 (constant)
                    float wv = (i < 4)  ? P4(i)
                             : (i < 8)  ? C4(ra, i - 4)
                             : (i < 12) ? C4(rb, i - 8)
                             :            N4(i - 12);
                    float xv = (k < 4) ? C4(xa, k) : C4(xb, k - 4);
                    acc[syi] += xv * wv;
                }
            }
#undef P4
#undef N4
        }

        xa = nxa; xb = nxb; ra = nra; rb = nrb; okc = okn;   // rotate
    }

    // Each wave owns 9 disjoint sims (its sx). Wave shuffle-reduce (fp32),
    // lane 0 stores one fp64 partial per sim into the TRANSPOSED layout.
#pragma unroll
    for (int s = 0; s < 9; ++s) {
        float v = acc[s];
        for (int off = 32; off; off >>= 1) v += __shfl_down(v, off, 64);
        if (lane == 0)
            g_part[strip][b * NS + sxi * 9 + s] = (double)v;
    }
}

// ONE block, 384 threads: thread t owns (b,sim)=t; iteration k reads
// g_part[k][0..323] = 2.6KB contiguous (coalesced), 64 independent
// iterations pipeline. Fixed k-order -> deterministic. Then per-batch
// first-index argmax (strict >, matches jnp.argmax) + tail write.
__global__ __launch_bounds__(384) void k_reduce(float* __restrict__ outTail) {
    int t = threadIdx.x;
    __shared__ double vals[BB * NS];
    if (t < BB * NS) {
        double s = 0.0;
#pragma unroll 4
        for (int k = 0; k < NSTRIPS; ++k) s += g_part[k][t];
        vals[t] = s;
    }
    __syncthreads();
    if (t < BB) {
        const double* v = vals + t * NS;
        int best = 0;
        double bv = v[0];
        for (int i = 1; i < NS; ++i)
            if (v[i] > bv) { bv = v[i]; best = i; }   // strict >: first index wins
        g_best[t] = best;
        outTail[t * 2]     = (float)(best / 9 - 4);
        outTail[t * 2 + 1] = (float)(best % 9 - 4);
    }
}

// Pure shift-copy: reads precomputed g_best[b] (wave-uniform scalar load).
// Copy body unchanged from R11-R17 (proven exact).
__global__ __launch_bounds__(256) void k_apply(const float* __restrict__ x,
                                               float* __restrict__ out) {
    int blk = blockIdx.x;
    int bc  = blk >> 8;                 // 256 blocks per image (512 rows / 2)
    int tid = threadIdx.x;
    int b   = bc / CC;

    int bi = g_best[b];
    int sx = bi / 9 - 4;
    int sy = bi % 9 - 4;

    int row = ((blk & 255) << 1) + (tid >> 7);
    int j0  = (tid & 127) << 2;
    int is  = row - sx;
    float4 v = make_float4(0.f, 0.f, 0.f, 0.f);
    if ((unsigned)is < HH) {
        const float* src = x + (size_t)bc * IMG + is * WW;
        int js0 = j0 - sy;
        if (js0 >= 0 && js0 + 3 < WW) {
            v = *(const float4*)(src + js0);   // 4B-aligned dwordx4, exact (R2-R18)
        } else {
            float* vv = (float*)&v;
#pragma unroll
            for (int k = 0; k < 4; ++k) {
                int js = js0 + k;
                if ((unsigned)js < WW) vv[k] = src[js];
            }
        }
    }
    *(float4*)(out + (size_t)bc * IMG + row * WW + j0) = v;
}

extern "C" void kernel_launch(void* const* d_in, const int* in_sizes, int n_in,
                              void* d_out, int out_size, void* d_ws, size_t ws_size,
                              hipStream_t stream) {
    const float* xref = (const float*)d_in[0];
    const float* x    = (const float*)d_in[1];
    float* out = (float*)d_out;
    (void)d_ws; (void)ws_size;          // workspace unused (poison fill is unconditional)

    k_sims<<<NBLK, 576, 0, stream>>>(xref, x);
    k_reduce<<<1, 384, 0, stream>>>(out + (size_t)BB * CHW);

    int applyBlocks = (BB * CC * HH) / 2;   // 3072
    k_apply<<<applyBlocks, 256, 0, stream>>>(x, out);
}